// Round 5
// baseline (183.596 us; speedup 1.0000x reference)
//
#include <hip/hip_runtime.h>
#include <hip/hip_bf16.h>

typedef __attribute__((ext_vector_type(4))) float f32x4;
typedef __attribute__((ext_vector_type(8))) __bf16 bf16x8;
typedef __attribute__((ext_vector_type(4))) __bf16 bf16x4;
typedef __attribute__((ext_vector_type(4))) unsigned int uint4v;

constexpr int M = 16384;
constexpr int N = 1024;
constexpr int K = 2048;
constexpr int BMR = 64;       // block rows; BN = N (full width, B read once/block)
constexpr int NT = K / 32;    // 64 K-tiles of BK=32
constexpr float BN_EPS = 1e-5f;
constexpr int TMB = M / BMR;  // 256 row-tiles (psum partials)

// async 16B global -> LDS (lds dest must be wave-uniform; HW adds lane*16)
#define GLOAD_LDS16(g, l)                                                      \
  __builtin_amdgcn_global_load_lds(                                            \
      (const __attribute__((address_space(1))) void*)(g),                      \
      (__attribute__((address_space(3))) void*)(l), 16, 0, 0)

#define SB0 __builtin_amdgcn_sched_barrier(0)
#define BARRIER __builtin_amdgcn_s_barrier()
#define VMC(n) asm volatile("s_waitcnt vmcnt(" #n ")" ::: "memory")
#define LGKM0 asm volatile("s_waitcnt lgkmcnt(0)" ::: "memory")

__device__ __forceinline__ unsigned sgnbf(float f) {
  return (f >= 0.f) ? 0x3F80u : 0xBF80u;
}
__global__ __launch_bounds__(256) void binw_kernel(
    const float* __restrict__ w, uint4v* __restrict__ wb) {
  size_t i = (size_t)blockIdx.x * 256 + threadIdx.x;
  const f32x4* win = (const f32x4*)w;
  f32x4 v0 = win[i * 2];
  f32x4 v1 = win[i * 2 + 1];
  uint4v o;
  o.x = sgnbf(v0[0]) | (sgnbf(v0[1]) << 16);
  o.y = sgnbf(v0[2]) | (sgnbf(v0[3]) << 16);
  o.z = sgnbf(v1[0]) | (sgnbf(v1[1]) << 16);
  o.w = sgnbf(v1[2]) | (sgnbf(v1[3]) << 16);
  wb[i] = o;
}

// ---- bf16 GEMM: 64x1024 stripe/block, 8 waves (1x8, each 64x128) ----
// A fp32 read ONCE per element (nontemporal -> reg, 2 tiles ahead; cvt +
// tiny 8KB/tile ds_write). B (4MB total, L2-resident per XCD) restaged per
// K-tile via gload_lds into 2-slot LDS, 64B rows + (row>>1)&3 involution
// (R0-verified: 0 bank conflicts). 2 phases/tile {8 ds_read; barrier;
// lgkm0; 16 MFMA; barrier} x2; counted vmcnt: B(t+1) staged at P0, drained
// at P1-end with vmcnt(1) keeping A(t+2) in flight (never drains fresh).
// Columns wave-partitioned -> psum/psq written directly (no LDS epilogue).
__global__ __launch_bounds__(512, 2) void gemm_bin_kernel(
    const float* __restrict__ Af, const unsigned short* __restrict__ B,
    float* __restrict__ Y, float* __restrict__ psum, float* __restrict__ psq) {
  __shared__ unsigned short Bs[2][32768];  // 128 KiB: [slot][row*32 + chunk*8]
  __shared__ unsigned short Asd[2][2048];  // 8 KiB: [slot][row*32 + chunk*8]

  const int tid = threadIdx.x;
  const int wid = tid >> 6;  // 0..7, wave owns cols [wid*128, +128)
  const int lane = tid & 63;
  const int frow = lane & 15;  // fragment row/col within 16x16
  const int fcb = lane >> 4;   // k chunk 0..3
  const int swq = (frow >> 1) & 3;

  const int tm = blockIdx.x;
  const size_t m0 = (size_t)tm * BMR;

  // frag read offsets (ushort idx); rows are 32 ushorts = 64B (verified-
  // conflict-free layout). +mi*512 / +nj*512 selects 16-row groups.
  const int aoff = frow * 32 + (fcb ^ swq) * 8;
  const int boff = (wid * 128 + frow) * 32 + (fcb ^ swq) * 8;

  // B staging: wave stages rows [wid*128,+128) = 8 gloads x 16 rows.
  // lane: row += lane>>2, lds chunk = lane&3, glob chunk = (lane&3)^((lane>>3)&3)
  const int bgc = (lane & 3) ^ ((lane >> 3) & 3);
  const unsigned short* pBg =
      B + (size_t)(wid * 128 + (lane >> 2)) * K + bgc * 8;

  // A staging: thread t: row rA = t>>3, fp32 quarter qA = t&7 (4 floats);
  // writes 4 bf16 (8B) at swizzled chunk (qA>>1)^((rA>>1)&3), half qA&1.
  const int rA = tid >> 3, qA = tid & 7;
  const float* pAg = Af + (m0 + rA) * (size_t)K + qA * 4;
  const int awoff = rA * 32 + (((qA >> 1) ^ ((rA >> 1) & 3)) * 8) + (qA & 1) * 4;

  f32x4 acc[4][8];
#pragma unroll
  for (int mi = 0; mi < 4; ++mi)
#pragma unroll
    for (int nj = 0; nj < 8; ++nj)
#pragma unroll
      for (int j = 0; j < 4; ++j) acc[mi][nj][j] = 0.f;

#define MFMA16(NJ0)                                                            \
  LGKM0;                                                                       \
  SB0;                                                                         \
  __builtin_amdgcn_s_setprio(1);                                               \
  _Pragma("unroll") for (int mi_ = 0; mi_ < 4; ++mi_)                          \
      _Pragma("unroll") for (int nj_ = 0; nj_ < 4; ++nj_)                      \
          acc[mi_][(NJ0) + nj_] = __builtin_amdgcn_mfma_f32_16x16x32_bf16(     \
              a_[mi_], b_[nj_], acc[mi_][(NJ0) + nj_], 0, 0, 0);               \
  __builtin_amdgcn_s_setprio(0);

  // MODE: 0 = steady, 1 = stage B only (pre-last), 2 = last (no stage)
#define ITER(S, NS, t, MODE, XL, XC)                                           \
  {                                                                            \
    bf16x8 a_[4], b_[4];                                                       \
    _Pragma("unroll") for (int i_ = 0; i_ < 4; ++i_) {                         \
      a_[i_] = *(const bf16x8*)&Asd[S][aoff + i_ * 512];                       \
      b_[i_] = *(const bf16x8*)&Bs[S][boff + i_ * 512];                        \
    }                                                                          \
    SB0;                                                                       \
    if (MODE == 0 || MODE == 1) {                                              \
      _Pragma("unroll") for (int u_ = 0; u_ < 8; ++u_)                         \
          GLOAD_LDS16(pBg + (size_t)u_ * 16 * K + (size_t)((t) + 1) * 32,      \
                      &Bs[NS][(wid * 128 + u_ * 16) * 32]);                    \
      SB0;                                                                     \
    }                                                                          \
    if (MODE == 0) {                                                           \
      XL = __builtin_nontemporal_load(                                         \
          (const f32x4*)(pAg + (size_t)((t) + 2) * 32));                       \
      SB0;                                                                     \
    }                                                                          \
    BARRIER;                                                                   \
    MFMA16(0);                                                                 \
    BARRIER;                                                                   \
    _Pragma("unroll") for (int i_ = 0; i_ < 4; ++i_) b_[i_] =                  \
        *(const bf16x8*)&Bs[S][boff + (4 + i_) * 512];                         \
    SB0;                                                                       \
    if (MODE != 2) { /* cvt A(t+1) -> slot NS (lgkm-drained pre-MFMA) */       \
      bf16x4 v_;                                                               \
      _Pragma("unroll") for (int j_ = 0; j_ < 4; ++j_)                         \
          v_[j_] = (__bf16)(XC)[j_];                                           \
      *(bf16x4*)&Asd[NS][awoff] = v_;                                          \
      SB0;                                                                     \
    }                                                                          \
    BARRIER;                                                                   \
    MFMA16(4);                                                                 \
    if (MODE == 0) VMC(1); /* drain B(t+1)x8, keep A(t+2) in flight */         \
    if (MODE == 1) VMC(0);                                                     \
    if (MODE != 2) BARRIER;                                                    \
  }

  // ---- prologue: stage tile 0 (B -> slot0 via gload, A -> cvt -> slot0) ----
  f32x4 xa, xb;
  xa = __builtin_nontemporal_load((const f32x4*)pAg);  // A(0)
  SB0;
#pragma unroll
  for (int u_ = 0; u_ < 8; ++u_)
    GLOAD_LDS16(pBg + (size_t)u_ * 16 * K, &Bs[0][(wid * 128 + u_ * 16) * 32]);
  SB0;
  xb = __builtin_nontemporal_load((const f32x4*)(pAg + 32));  // A(1)
  SB0;
  {
    bf16x4 v_;  // compiler auto-waits xa (oldest in queue)
#pragma unroll
    for (int j_ = 0; j_ < 4; ++j_) v_[j_] = (__bf16)xa[j_];
    *(bf16x4*)&Asd[0][awoff] = v_;
  }
  VMC(1);  // drain B(0)x8, keep A(1)
  LGKM0;
  BARRIER;

  // ---- main loop: 64 K-tiles (even t: load xa / cvt xb, odd: swapped) ----
  for (int t = 0; t < NT - 4; t += 2) {
    ITER(0, 1, t, 0, xa, xb);
    ITER(1, 0, t + 1, 0, xb, xa);
  }
  ITER(0, 1, NT - 4, 0, xa, xb);  // t=60: loads A(62), cvt A(61)
  ITER(1, 0, NT - 3, 0, xb, xa);  // t=61: loads A(63), cvt A(62)
  ITER(0, 1, NT - 2, 1, xa, xb);  // t=62: stage B(63), cvt A(63)
  ITER(1, 0, NT - 1, 2, xa, xa);  // t=63: no stage, no barrier

  // ---- epilogue: column stats (wave-partitioned cols, direct store) ----
  // C/D layout: col = wid*128 + nj*16 + frow, row = m0 + mi*16 + fcb*4 + j
#pragma unroll
  for (int nj = 0; nj < 8; ++nj) {
    float s = 0.f, q = 0.f;
#pragma unroll
    for (int mi = 0; mi < 4; ++mi)
#pragma unroll
      for (int j = 0; j < 4; ++j) {
        float v = acc[mi][nj][j];
        s += v;
        q += v * v;
      }
    s += __shfl_xor(s, 16);  // reduce over fcb (lane bits 4-5)
    s += __shfl_xor(s, 32);
    q += __shfl_xor(q, 16);
    q += __shfl_xor(q, 32);
    if (fcb == 0) {
      psum[(size_t)tm * N + wid * 128 + nj * 16 + frow] = s;
      psq[(size_t)tm * N + wid * 128 + nj * 16 + frow] = q;
    }
  }

  // ---- Y store fp32, nontemporal (protect L2-resident B) ----
#pragma unroll
  for (int mi = 0; mi < 4; ++mi) {
#pragma unroll
    for (int nj = 0; nj < 8; ++nj) {
      float* yp =
          Y + (m0 + mi * 16 + fcb * 4) * N + wid * 128 + nj * 16 + frow;
#pragma unroll
      for (int j = 0; j < 4; ++j)
        __builtin_nontemporal_store(acc[mi][nj][j], yp + (size_t)j * N);
    }
  }
}

// ---- finalize BN stats -> per-column scale/shift ----
__global__ __launch_bounds__(256) void bnstats_kernel(
    const float* __restrict__ psum, const float* __restrict__ psq,
    const float* __restrict__ gamma, const float* __restrict__ beta,
    float* __restrict__ scale, float* __restrict__ shift) {
  const int c = blockIdx.x * 256 + threadIdx.x;
  float s0 = 0.f, s1 = 0.f, q0 = 0.f, q1 = 0.f;
  for (int i = 0; i < TMB; i += 2) {
    s0 += psum[i * N + c];
    s1 += psum[(i + 1) * N + c];
    q0 += psq[i * N + c];
    q1 += psq[(i + 1) * N + c];
  }
  const float s = s0 + s1, q = q0 + q1;
  const float mean = s * (1.f / (float)M);
  const float var = q * (1.f / (float)M) - mean * mean;
  const float inv = rsqrtf(var + BN_EPS);
  const float sc = gamma[c] * inv;
  scale[c] = sc;
  shift[c] = beta[c] - mean * sc;
}

// ---- apply BN in place on fp32 Y (= d_out), 4 floats / thread ----
__global__ __launch_bounds__(256) void bnapply_kernel(
    float* __restrict__ Y, const float* __restrict__ scale,
    const float* __restrict__ shift) {
  const size_t i = (size_t)blockIdx.x * 256 + threadIdx.x;
  f32x4 y = ((const f32x4*)Y)[i];
  const int c = (int)((i * 4) & (N - 1));
  f32x4 sc = *(const f32x4*)&scale[c];
  f32x4 sh = *(const f32x4*)&shift[c];
  ((f32x4*)Y)[i] = y * sc + sh;
}

extern "C" void kernel_launch(void* const* d_in, const int* in_sizes, int n_in,
                              void* d_out, int out_size, void* d_ws,
                              size_t ws_size, hipStream_t stream) {
  const float* x = (const float*)d_in[0];
  const float* w = (const float*)d_in[1];
  // d_in[2] = bias: a per-column constant shift cancels exactly in BatchNorm
  const float* gamma = (const float*)d_in[3];
  const float* beta = (const float*)d_in[4];
  float* Y = (float*)d_out;  // y staged here fp32, normalized in place

  char* ws = (char*)d_ws;
  uint4v* wb = (uint4v*)ws;  // 4 MiB
  float* psum = (float*)(ws + (size_t)N * K * 2);
  float* psq = psum + (size_t)TMB * N;  // 1 MiB each
  float* scale = psq + (size_t)TMB * N;
  float* shift = scale + N;

  binw_kernel<<<(N * K / 8) / 256, 256, 0, stream>>>(w, wb);
  gemm_bin_kernel<<<TMB, 512, 0, stream>>>(x, (const unsigned short*)wb, Y,
                                           psum, psq);
  bnstats_kernel<<<N / 256, 256, 0, stream>>>(psum, psq, gamma, beta, scale,
                                              shift);
  bnapply_kernel<<<(M * N / 4) / 256, 256, 0, stream>>>(Y, scale, shift);
}